// Round 8
// baseline (127.457 us; speedup 1.0000x reference)
//
#include <hip/hip_runtime.h>
#include <math.h>

#define EPSF 1e-15f
#define CLAMPF 1e-7f
#define D 128
#define ELLW 64   // max degree bucket; src ~Poisson(12.8), det. max deg ~33

typedef float v2f __attribute__((ext_vector_type(2)));

__device__ __forceinline__ float rcpf(float x) { return __builtin_amdgcn_rcpf(x); }
__device__ __forceinline__ float rsqf(float x) { return __builtin_amdgcn_rsqf(x); }

__device__ __forceinline__ v2f vfma2(v2f a, v2f b, v2f c) {
#if __has_builtin(__builtin_elementwise_fma)
    return __builtin_elementwise_fma(a, b, c);
#else
    v2f r; r.x = fmaf(a.x, b.x, c.x); r.y = fmaf(a.y, b.y, c.y); return r;
#endif
}

// tanh(z) with arg 2z: tanh(z) = 1 - 2/(e^{2z}+1)
__device__ __forceinline__ float tanh_fast2(float z2) {
    float e2 = __expf(z2);
    return 1.0f - 2.0f * rcpf(e2 + 1.0f);
}

// v += dpp_perm<CTRL>(v); sources always valid within row -> old=src, bc=false
template<int CTRL>
__device__ __forceinline__ float dpp_add(float v) {
    int s = __builtin_bit_cast(int, v);
    int m = __builtin_amdgcn_update_dpp(s, s, CTRL, 0xF, 0xF, false);
    return v + __builtin_bit_cast(float, m);
}
// full sum within each 8-lane group (all lanes get the result):
// quad_perm xor1 (0xB1), quad_perm xor2 (0x4E), row_half_mirror (0x141)
__device__ __forceinline__ float red8(float v) {
    v = dpp_add<0xB1>(v);
    v = dpp_add<0x4E>(v);
    v = dpp_add<0x141>(v);
    return v;
}

// ---- single-pass ELL build: ell[src*ELLW + slot] = dst | etype<<20 ----
__global__ void build_ell_kernel(const int* __restrict__ src,
                                 const int* __restrict__ dst,
                                 const int* __restrict__ etype,
                                 int* __restrict__ cnt,
                                 int* __restrict__ ell, int n_edges) {
    int i = blockIdx.x * blockDim.x + threadIdx.x;
    int base = i * 4;
    if (base >= n_edges) return;
    if (base + 4 <= n_edges) {
        int4 s = *(const int4*)(src + base);
        int4 d = *(const int4*)(dst + base);
        int4 e = *(const int4*)(etype + base);
        int p;
        p = atomicAdd(cnt + s.x, 1); if (p < ELLW) ell[s.x * ELLW + p] = d.x | (e.x << 20);
        p = atomicAdd(cnt + s.y, 1); if (p < ELLW) ell[s.y * ELLW + p] = d.y | (e.y << 20);
        p = atomicAdd(cnt + s.z, 1); if (p < ELLW) ell[s.z * ELLW + p] = d.z | (e.z << 20);
        p = atomicAdd(cnt + s.w, 1); if (p < ELLW) ell[s.w * ELLW + p] = d.w | (e.w << 20);
    } else {
        for (int k = base; k < n_edges; ++k) {
            int p = atomicAdd(cnt + src[k], 1);
            if (p < ELLW) ell[src[k] * ELLW + p] = dst[k] | (etype[k] << 20);
        }
    }
}

// ---- aggregation: one wave per node; 8 subgroups x 8 lanes; 16 elems/lane ----
__global__ __launch_bounds__(256)
void node_agg_kernel(const float* __restrict__ slot,
                     const float* __restrict__ intm_virt,  // intm - n_slot*D
                     const float* __restrict__ rel,
                     const int* __restrict__ ell,
                     const int* __restrict__ cnt,
                     float* __restrict__ out,
                     int n_slot, int n_nodes) {
    int wid  = (blockIdx.x * blockDim.x + threadIdx.x) >> 6;
    int lane = threadIdx.x & 63;
    if (wid >= n_nodes) return;
    int sl = lane & 7;      // slice within row (16 elems)
    int g  = lane >> 3;     // subgroup id (edge offset, 0..7)

    // ---- per-node invariants: x = expmap0(embed[node]) ----
    const float* xrow = ((wid < n_slot) ? slot : intm_virt) + (size_t)wid * D + sl * 16;
    v2f x[8];
    {
        float4 f0 = ((const float4*)xrow)[0];
        float4 f1 = ((const float4*)xrow)[1];
        float4 f2 = ((const float4*)xrow)[2];
        float4 f3 = ((const float4*)xrow)[3];
        x[0] = (v2f){f0.x, f0.y}; x[1] = (v2f){f0.z, f0.w};
        x[2] = (v2f){f1.x, f1.y}; x[3] = (v2f){f1.z, f1.w};
        x[4] = (v2f){f2.x, f2.y}; x[5] = (v2f){f2.z, f2.w};
        x[6] = (v2f){f3.x, f3.y}; x[7] = (v2f){f3.z, f3.w};
    }
    v2f ssv = x[0] * x[0];
    #pragma unroll
    for (int i = 1; i < 8; ++i) ssv = vfma2(x[i], x[i], ssv);
    float ss = red8(ssv.x + ssv.y);

    float irn = rsqf(fmaxf(ss, EPSF));
    float n   = ss * irn;                  // ||embed||
    float thn = tanh_fast2(2.0f * n);
    float tf  = thn * irn;                 // tanh(n)/n
    float x2  = thn * thn;                 // ||x||^2
    v2f tfv = (v2f){tf, tf};
    #pragma unroll
    for (int i = 0; i < 8; ++i) x[i] *= tfv;

    float fac  = 1.0f - x2;
    float fac2 = fac * fac;

    int cn = cnt[wid];
    int m  = (cn < ELLW) ? cn : ELLW;

    // whole ELL row into registers (one coalesced load per wave)
    const int* erow = ell + (size_t)wid * ELLW;
    int pk_all = (lane < m) ? erow[lane] : 0;

    float accx = 0.0f;
    v2f acc[8];
    #pragma unroll
    for (int i = 0; i < 8; ++i) acc[i] = (v2f){0.f, 0.f};

    for (int p = 0; p < m; p += 8) {
        int ep = p + g;
        bool ok = ep < m;
        int pk = __shfl(pk_all, ep, 64);
        unsigned di = (unsigned)pk & 0xFFFFF;
        unsigned ri = ((unsigned)pk) >> 20;

        const float* drow = (((int)di < n_slot) ? slot : intm_virt)
                            + (size_t)di * D + sl * 16;
        const float* rrow = rel + (size_t)ri * D + sl * 16;   // 8KB table: L1-hit

        float4 d0 = ((const float4*)drow)[0];
        float4 d1 = ((const float4*)drow)[1];
        float4 d2 = ((const float4*)drow)[2];
        float4 d3 = ((const float4*)drow)[3];
        float4 r0 = ((const float4*)rrow)[0];
        float4 r1 = ((const float4*)rrow)[1];
        float4 r2 = ((const float4*)rrow)[2];
        float4 r3 = ((const float4*)rrow)[3];

        v2f t[8];
        t[0] = (v2f){d0.x + r0.x, d0.y + r0.y};
        t[1] = (v2f){d0.z + r0.z, d0.w + r0.w};
        t[2] = (v2f){d1.x + r1.x, d1.y + r1.y};
        t[3] = (v2f){d1.z + r1.z, d1.w + r1.w};
        t[4] = (v2f){d2.x + r2.x, d2.y + r2.y};
        t[5] = (v2f){d2.z + r2.z, d2.w + r2.w};
        t[6] = (v2f){d3.x + r3.x, d3.y + r3.y};
        t[7] = (v2f){d3.z + r3.z, d3.w + r3.w};

        v2f ttv = t[0] * t[0];
        v2f xtv = x[0] * t[0];
        #pragma unroll
        for (int i = 1; i < 8; ++i) {
            ttv = vfma2(t[i], t[i], ttv);
            xtv = vfma2(x[i], t[i], xtv);
        }
        float tt = red8(ttv.x + ttv.y);
        float xt = red8(xtv.x + xtv.y);

        // slimmed chain: 0.5*lam*||u|| == ||t||  (fac cancels)
        float irt = rsqf(fmaxf(tt, EPSF));
        float st2 = 2.0f * tt * irt;            // 2*||t||
        float th  = tanh_fast2(st2);            // tanh(||t||)
        float w   = th * irt;                   // tanh(||t||)/||t||
        float y2  = th * th;                    // ||second||^2
        float xy  = w * xt;                     // x . second
        float two_xy = xy + xy;
        float opx = 1.0f + two_xy;
        float a   = opx + y2;
        float den = fmaf(x2, y2, opx);
        float invden = rcpf(fmaxf(den, EPSF));
        float poly = fmaf(a * a, x2, fmaf(a * fac, two_xy, fac2 * y2));
        float qq   = invden * invden * poly;    // ||q||^2
        float irq  = rsqf(fmaxf(qq, EPSF));
        float nq   = qq * irq;
        float cl   = fminf(nq, 1.0f - CLAMPF);
        float at   = 0.5f * __logf((1.0f + cl) * rcpf(1.0f - cl));  // artanh
        float sc2  = at * irq;
        float k    = sc2 * invden;
        float cx   = k * a;
        float ct   = k * w * fac;
        if (!ok) { cx = 0.0f; ct = 0.0f; }

        accx += cx;
        v2f ctv = (v2f){ct, ct};
        #pragma unroll
        for (int i = 0; i < 8; ++i) acc[i] = vfma2(ctv, t[i], acc[i]);
    }

    // fold accx*x into accumulators (x identical across subgroups)
    v2f axv = (v2f){accx, accx};
    #pragma unroll
    for (int i = 0; i < 8; ++i) acc[i] = vfma2(axv, x[i], acc[i]);

    // cross-subgroup reduction (xor 8, 16, 32) over 16 scalars
    float v[16];
    #pragma unroll
    for (int i = 0; i < 8; ++i) { v[2*i] = acc[i].x; v[2*i+1] = acc[i].y; }
    #pragma unroll
    for (int d = 8; d < 64; d <<= 1) {
        #pragma unroll
        for (int j = 0; j < 16; ++j) v[j] += __shfl_xor(v[j], d, 64);
    }

    if (lane < 8) {
        float invcnt = rcpf(fmaxf((float)cn, 1.0f));
        float* orow = out + (size_t)wid * D + sl * 16;
        float4 w0 = make_float4(v[0]*invcnt,  v[1]*invcnt,  v[2]*invcnt,  v[3]*invcnt);
        float4 w1 = make_float4(v[4]*invcnt,  v[5]*invcnt,  v[6]*invcnt,  v[7]*invcnt);
        float4 w2 = make_float4(v[8]*invcnt,  v[9]*invcnt,  v[10]*invcnt, v[11]*invcnt);
        float4 w3 = make_float4(v[12]*invcnt, v[13]*invcnt, v[14]*invcnt, v[15]*invcnt);
        ((float4*)orow)[0] = w0;
        ((float4*)orow)[1] = w1;
        ((float4*)orow)[2] = w2;
        ((float4*)orow)[3] = w3;
    }
}

extern "C" void kernel_launch(void* const* d_in, const int* in_sizes, int n_in,
                              void* d_out, int out_size, void* d_ws, size_t ws_size,
                              hipStream_t stream) {
    const float* slot = (const float*)d_in[0];
    const float* intm = (const float*)d_in[1];
    const float* rel  = (const float*)d_in[2];
    const int*   src  = (const int*)d_in[3];
    const int*   dst  = (const int*)d_in[4];
    const int*   etyp = (const int*)d_in[5];

    int n_slot  = in_sizes[0] / D;
    int n_int   = in_sizes[1] / D;
    int n_nodes = n_slot + n_int;
    int n_edges = in_sizes[3];

    float* out = (float*)d_out;
    const float* intm_virt = intm - (size_t)n_slot * D;

    int* cnt = (int*)d_ws;
    int* ell = cnt + n_nodes;

    hipMemsetAsync(cnt, 0, (size_t)n_nodes * sizeof(int), stream);

    {   // one-pass ELL build (4 edges/thread)
        int threads = 256;
        int nthreads = (n_edges + 3) / 4;
        int blocks = (nthreads + threads - 1) / threads;
        build_ell_kernel<<<blocks, threads, 0, stream>>>(src, dst, etyp, cnt, ell,
                                                         n_edges);
    }
    {   // per-node aggregation
        int threads = 256;
        int blocks = (n_nodes * 64 + threads - 1) / threads;
        node_agg_kernel<<<blocks, threads, 0, stream>>>(slot, intm_virt, rel, ell,
                                                        cnt, out, n_slot, n_nodes);
    }
}

// Round 9
// 100.648 us; speedup vs baseline: 1.2664x; 1.2664x over previous
//
#include <hip/hip_runtime.h>
#include <math.h>

#define EPSF 1e-15f
#define CLAMPF 1e-7f
#define D 128
#define ELLW 64   // max degree bucket; src ~Poisson(12.8), det. max deg ~33

typedef float v2f __attribute__((ext_vector_type(2)));

__device__ __forceinline__ float rcpf(float x) { return __builtin_amdgcn_rcpf(x); }
__device__ __forceinline__ float rsqf(float x) { return __builtin_amdgcn_rsqf(x); }

__device__ __forceinline__ v2f vfma2(v2f a, v2f b, v2f c) {
#if __has_builtin(__builtin_elementwise_fma)
    return __builtin_elementwise_fma(a, b, c);
#else
    v2f r; r.x = fmaf(a.x, b.x, c.x); r.y = fmaf(a.y, b.y, c.y); return r;
#endif
}

// tanh(z) with arg 2z: tanh(z) = 1 - 2/(e^{2z}+1)
__device__ __forceinline__ float tanh_fast2(float z2) {
    float e2 = __expf(z2);
    return 1.0f - 2.0f * rcpf(e2 + 1.0f);
}

// v += row_ror<CTRL>(v); ror sources always valid -> old=src, bound_ctrl=false
template<int CTRL>
__device__ __forceinline__ float dpp_add(float v) {
    int s = __builtin_bit_cast(int, v);
    int m = __builtin_amdgcn_update_dpp(s, s, CTRL, 0xF, 0xF, false);
    return v + __builtin_bit_cast(float, m);
}
// full sum within each 16-lane row (all lanes get the result)
__device__ __forceinline__ float red16(float v) {
    v = dpp_add<0x128>(v);  // ror 8
    v = dpp_add<0x124>(v);  // ror 4
    v = dpp_add<0x122>(v);  // ror 2
    v = dpp_add<0x121>(v);  // ror 1
    return v;
}

struct v2x2 { v2f lo, hi; };
__device__ __forceinline__ v2x2 ld8(const float* p) {
    float4 f = *(const float4*)p;
    v2x2 r; r.lo = (v2f){f.x, f.y}; r.hi = (v2f){f.z, f.w}; return r;
}

// ---- single-pass ELL build: ell[src*ELLW + slot] = dst | etype<<20 ----
__global__ void build_ell_kernel(const int* __restrict__ src,
                                 const int* __restrict__ dst,
                                 const int* __restrict__ etype,
                                 int* __restrict__ cnt,
                                 int* __restrict__ ell, int n_edges) {
    int i = blockIdx.x * blockDim.x + threadIdx.x;
    int base = i * 4;
    if (base >= n_edges) return;
    if (base + 4 <= n_edges) {
        int4 s = *(const int4*)(src + base);
        int4 d = *(const int4*)(dst + base);
        int4 e = *(const int4*)(etype + base);
        int p;
        p = atomicAdd(cnt + s.x, 1); if (p < ELLW) ell[s.x * ELLW + p] = d.x | (e.x << 20);
        p = atomicAdd(cnt + s.y, 1); if (p < ELLW) ell[s.y * ELLW + p] = d.y | (e.y << 20);
        p = atomicAdd(cnt + s.z, 1); if (p < ELLW) ell[s.z * ELLW + p] = d.z | (e.z << 20);
        p = atomicAdd(cnt + s.w, 1); if (p < ELLW) ell[s.w * ELLW + p] = d.w | (e.w << 20);
    } else {
        for (int k = base; k < n_edges; ++k) {
            int p = atomicAdd(cnt + src[k], 1);
            if (p < ELLW) ell[src[k] * ELLW + p] = dst[k] | (etype[k] << 20);
        }
    }
}

// ---- aggregation: one wave per node; 4 subgroups x 16 lanes; 8 elems/lane;
//      2-edge manual unroll per subgroup per iteration ----
__global__ __launch_bounds__(256)
void node_agg_kernel(const float* __restrict__ slot,
                     const float* __restrict__ intm_virt,  // intm - n_slot*D
                     const float* __restrict__ rel,
                     const int* __restrict__ ell,
                     const int* __restrict__ cnt,
                     float* __restrict__ out,
                     int n_slot, int n_nodes) {
    int wid  = (blockIdx.x * blockDim.x + threadIdx.x) >> 6;
    int lane = threadIdx.x & 63;
    if (wid >= n_nodes) return;
    int sl = lane & 15;
    int g  = lane >> 4;

    // ---- per-node invariants: x = expmap0(embed[node]) ----
    const float* xrow = ((wid < n_slot) ? slot : intm_virt) + (size_t)wid * D + sl * 8;
    v2x2 ea = ld8(xrow);
    v2x2 eb = ld8(xrow + 4);
    v2f ssv = ea.lo * ea.lo;
    ssv = vfma2(ea.hi, ea.hi, ssv);
    ssv = vfma2(eb.lo, eb.lo, ssv);
    ssv = vfma2(eb.hi, eb.hi, ssv);
    float ss = red16(ssv.x + ssv.y);

    float irn = rsqf(fmaxf(ss, EPSF));
    float n   = ss * irn;                  // ||embed||
    float thn = tanh_fast2(2.0f * n);
    float tf  = thn * irn;                 // tanh(n)/n
    float x2  = thn * thn;                 // ||x||^2
    v2f tfv = (v2f){tf, tf};
    v2f x0 = ea.lo * tfv, x1 = ea.hi * tfv;
    v2f x2v_ = eb.lo * tfv, x3 = eb.hi * tfv;

    float fac  = 1.0f - x2;
    float fac2 = fac * fac;

    int cn = cnt[wid];
    int m  = (cn < ELLW) ? cn : ELLW;
    const int* erow = ell + (size_t)wid * ELLW;

    // whole ELL row into registers (one coalesced load per wave)
    int pk_all = (lane < m) ? erow[lane] : 0;

    float accx = 0.0f;
    v2f ac0 = (v2f){0.f, 0.f}, ac1 = ac0, ac2 = ac0, ac3 = ac0;

    for (int p = 0; p < m; p += 8) {
        int ep0 = p + g;
        int ep1 = p + 4 + g;
        bool ok0 = ep0 < m;
        bool ok1 = ep1 < m;
        int pk0 = __shfl(pk_all, ep0 & 63, 64);
        int pk1 = __shfl(pk_all, ep1 & 63, 64);
        unsigned di0 = (unsigned)pk0 & 0xFFFFF, ri0 = ((unsigned)pk0) >> 20;
        unsigned di1 = (unsigned)pk1 & 0xFFFFF, ri1 = ((unsigned)pk1) >> 20;

        const float* drow0 = (((int)di0 < n_slot) ? slot : intm_virt)
                             + (size_t)di0 * D + sl * 8;
        const float* drow1 = (((int)di1 < n_slot) ? slot : intm_virt)
                             + (size_t)di1 * D + sl * 8;
        const float* rrow0 = rel + (size_t)ri0 * D + sl * 8;   // 8KB: L1-hit
        const float* rrow1 = rel + (size_t)ri1 * D + sl * 8;

        v2x2 dA0 = ld8(drow0);
        v2x2 dB0 = ld8(drow0 + 4);
        v2x2 dA1 = ld8(drow1);
        v2x2 dB1 = ld8(drow1 + 4);
        v2x2 rA0 = ld8(rrow0);
        v2x2 rB0 = ld8(rrow0 + 4);
        v2x2 rA1 = ld8(rrow1);
        v2x2 rB1 = ld8(rrow1 + 4);

        // edge 0 tangent
        v2f s0 = dA0.lo + rA0.lo;
        v2f s1 = dA0.hi + rA0.hi;
        v2f s2 = dB0.lo + rB0.lo;
        v2f s3 = dB0.hi + rB0.hi;
        // edge 1 tangent
        v2f u0 = dA1.lo + rA1.lo;
        v2f u1 = dA1.hi + rA1.hi;
        v2f u2 = dB1.lo + rB1.lo;
        v2f u3 = dB1.hi + rB1.hi;

        v2f ttv0 = s0 * s0;
        ttv0 = vfma2(s1, s1, ttv0);
        ttv0 = vfma2(s2, s2, ttv0);
        ttv0 = vfma2(s3, s3, ttv0);
        v2f xtv0 = x0 * s0;
        xtv0 = vfma2(x1, s1, xtv0);
        xtv0 = vfma2(x2v_, s2, xtv0);
        xtv0 = vfma2(x3, s3, xtv0);

        v2f ttv1 = u0 * u0;
        ttv1 = vfma2(u1, u1, ttv1);
        ttv1 = vfma2(u2, u2, ttv1);
        ttv1 = vfma2(u3, u3, ttv1);
        v2f xtv1 = x0 * u0;
        xtv1 = vfma2(x1, u1, xtv1);
        xtv1 = vfma2(x2v_, u2, xtv1);
        xtv1 = vfma2(x3, u3, xtv1);

        float tt0 = red16(ttv0.x + ttv0.y);
        float xt0 = red16(xtv0.x + xtv0.y);
        float tt1 = red16(ttv1.x + ttv1.y);
        float xt1 = red16(xtv1.x + xtv1.y);

        // slimmed chain (fac cancels: 0.5*lam*||u|| == ||t||), 2 edges interleaved
        float irt0 = rsqf(fmaxf(tt0, EPSF));
        float irt1 = rsqf(fmaxf(tt1, EPSF));
        float th0  = tanh_fast2(2.0f * tt0 * irt0);
        float th1  = tanh_fast2(2.0f * tt1 * irt1);
        float w0   = th0 * irt0;
        float w1   = th1 * irt1;
        float y20  = th0 * th0;
        float y21  = th1 * th1;
        float xy0  = w0 * xt0;
        float xy1  = w1 * xt1;
        float txy0 = xy0 + xy0;
        float txy1 = xy1 + xy1;
        float opx0 = 1.0f + txy0;
        float opx1 = 1.0f + txy1;
        float a0   = opx0 + y20;
        float a1   = opx1 + y21;
        float den0 = fmaf(x2, y20, opx0);
        float den1 = fmaf(x2, y21, opx1);
        float ivd0 = rcpf(fmaxf(den0, EPSF));
        float ivd1 = rcpf(fmaxf(den1, EPSF));
        float pl0  = fmaf(a0 * a0, x2, fmaf(a0 * fac, txy0, fac2 * y20));
        float pl1  = fmaf(a1 * a1, x2, fmaf(a1 * fac, txy1, fac2 * y21));
        float qq0  = ivd0 * ivd0 * pl0;
        float qq1  = ivd1 * ivd1 * pl1;
        float irq0 = rsqf(fmaxf(qq0, EPSF));
        float irq1 = rsqf(fmaxf(qq1, EPSF));
        float nq0  = qq0 * irq0;
        float nq1  = qq1 * irq1;
        float cl0  = fminf(nq0, 1.0f - CLAMPF);
        float cl1  = fminf(nq1, 1.0f - CLAMPF);
        float at0  = 0.5f * __logf((1.0f + cl0) * rcpf(1.0f - cl0));
        float at1  = 0.5f * __logf((1.0f + cl1) * rcpf(1.0f - cl1));
        float sA0  = at0 * irq0;
        float sA1  = at1 * irq1;
        float k0   = sA0 * ivd0;
        float k1   = sA1 * ivd1;
        float cx0  = k0 * a0;
        float cx1  = k1 * a1;
        float ct0  = k0 * w0 * fac;
        float ct1  = k1 * w1 * fac;
        if (!ok0) { cx0 = 0.0f; ct0 = 0.0f; }
        if (!ok1) { cx1 = 0.0f; ct1 = 0.0f; }

        accx += cx0 + cx1;
        v2f c0 = (v2f){ct0, ct0};
        v2f c1 = (v2f){ct1, ct1};
        ac0 = vfma2(c0, s0, ac0); ac0 = vfma2(c1, u0, ac0);
        ac1 = vfma2(c0, s1, ac1); ac1 = vfma2(c1, u1, ac1);
        ac2 = vfma2(c0, s2, ac2); ac2 = vfma2(c1, u2, ac2);
        ac3 = vfma2(c0, s3, ac3); ac3 = vfma2(c1, u3, ac3);
    }

    // fold accx*x into accumulators (x identical across subgroups)
    v2f axv = (v2f){accx, accx};
    ac0 = vfma2(axv, x0, ac0);
    ac1 = vfma2(axv, x1, ac1);
    ac2 = vfma2(axv, x2v_, ac2);
    ac3 = vfma2(axv, x3, ac3);

    // cross-subgroup reduction (xor 16, 32)
    float v0 = ac0.x, v1 = ac0.y, v2 = ac1.x, v3 = ac1.y;
    float v4 = ac2.x, v5 = ac2.y, v6 = ac3.x, v7 = ac3.y;
    #pragma unroll
    for (int d = 16; d < 64; d <<= 1) {
        v0 += __shfl_xor(v0, d, 64);
        v1 += __shfl_xor(v1, d, 64);
        v2 += __shfl_xor(v2, d, 64);
        v3 += __shfl_xor(v3, d, 64);
        v4 += __shfl_xor(v4, d, 64);
        v5 += __shfl_xor(v5, d, 64);
        v6 += __shfl_xor(v6, d, 64);
        v7 += __shfl_xor(v7, d, 64);
    }

    if (lane < 16) {
        float invcnt = rcpf(fmaxf((float)cn, 1.0f));
        float4 w0 = make_float4(v0 * invcnt, v1 * invcnt, v2 * invcnt, v3 * invcnt);
        float4 w1 = make_float4(v4 * invcnt, v5 * invcnt, v6 * invcnt, v7 * invcnt);
        float* orow = out + (size_t)wid * D + sl * 8;
        *(float4*)(orow)     = w0;
        *(float4*)(orow + 4) = w1;
    }
}

extern "C" void kernel_launch(void* const* d_in, const int* in_sizes, int n_in,
                              void* d_out, int out_size, void* d_ws, size_t ws_size,
                              hipStream_t stream) {
    const float* slot = (const float*)d_in[0];
    const float* intm = (const float*)d_in[1];
    const float* rel  = (const float*)d_in[2];
    const int*   src  = (const int*)d_in[3];
    const int*   dst  = (const int*)d_in[4];
    const int*   etyp = (const int*)d_in[5];

    int n_slot  = in_sizes[0] / D;
    int n_int   = in_sizes[1] / D;
    int n_nodes = n_slot + n_int;
    int n_edges = in_sizes[3];

    float* out = (float*)d_out;
    const float* intm_virt = intm - (size_t)n_slot * D;

    int* cnt = (int*)d_ws;
    int* ell = cnt + n_nodes;

    hipMemsetAsync(cnt, 0, (size_t)n_nodes * sizeof(int), stream);

    {   // one-pass ELL build (4 edges/thread)
        int threads = 256;
        int nthreads = (n_edges + 3) / 4;
        int blocks = (nthreads + threads - 1) / threads;
        build_ell_kernel<<<blocks, threads, 0, stream>>>(src, dst, etyp, cnt, ell,
                                                         n_edges);
    }
    {   // per-node aggregation
        int threads = 256;
        int blocks = (n_nodes * 64 + threads - 1) / threads;
        node_agg_kernel<<<blocks, threads, 0, stream>>>(slot, intm_virt, rel, ell,
                                                        cnt, out, n_slot, n_nodes);
    }
}

// Round 11
// 94.576 us; speedup vs baseline: 1.3477x; 1.0642x over previous
//
#include <hip/hip_runtime.h>
#include <math.h>

#define EPSF 1e-15f
#define CLAMPF 1e-7f
#define D 128
#define ELLW 64          // max degree bucket; src ~Poisson(12.8), det. max deg ~33
#define LOG2E2 2.885390081777927f      // 2*log2(e)
#define HALF_LN2 0.34657359027997264f  // 0.5*ln(2):  0.5*ln(x) == HALF_LN2*log2(x)

typedef float v2f __attribute__((ext_vector_type(2)));

__device__ __forceinline__ float rcpf(float x) { return __builtin_amdgcn_rcpf(x); }
__device__ __forceinline__ float rsqf(float x) { return __builtin_amdgcn_rsqf(x); }
__device__ __forceinline__ float exp2h(float x) { return __builtin_amdgcn_exp2f(x); }   // v_exp_f32: 2^x
__device__ __forceinline__ float log2h(float x) { return __builtin_amdgcn_logf(x); }    // v_log_f32: log2(x)

__device__ __forceinline__ v2f vfma2(v2f a, v2f b, v2f c) {
#if __has_builtin(__builtin_elementwise_fma)
    return __builtin_elementwise_fma(a, b, c);
#else
    v2f r; r.x = fmaf(a.x, b.x, c.x); r.y = fmaf(a.y, b.y, c.y); return r;
#endif
}

// tanh(z) given zl = 2*log2(e)*z :  tanh(z) = 1 - 2/(2^zl + 1)
__device__ __forceinline__ float tanh_exp2(float zl) {
    float e2 = exp2h(zl);
    return 1.0f - 2.0f * rcpf(e2 + 1.0f);
}

// v += row_ror<CTRL>(v); ror sources always valid -> old=src, bound_ctrl=false
template<int CTRL>
__device__ __forceinline__ float dpp_add(float v) {
    int s = __builtin_bit_cast(int, v);
    int m = __builtin_amdgcn_update_dpp(s, s, CTRL, 0xF, 0xF, false);
    return v + __builtin_bit_cast(float, m);
}
// full sum within each 16-lane row (all lanes get the result)
__device__ __forceinline__ float red16(float v) {
    v = dpp_add<0x128>(v);  // ror 8
    v = dpp_add<0x124>(v);  // ror 4
    v = dpp_add<0x122>(v);  // ror 2
    v = dpp_add<0x121>(v);  // ror 1
    return v;
}

struct v2x2 { v2f lo, hi; };
__device__ __forceinline__ v2x2 ld8(const float* p) {
    float4 f = *(const float4*)p;
    v2x2 r; r.lo = (v2f){f.x, f.y}; r.hi = (v2f){f.z, f.w}; return r;
}

// ---- single-pass ELL build: ell[src*ELLW + slot] = dst | etype<<20 ----
__global__ void build_ell_kernel(const int* __restrict__ src,
                                 const int* __restrict__ dst,
                                 const int* __restrict__ etype,
                                 int* __restrict__ cnt,
                                 int* __restrict__ ell, int n_edges) {
    int i = blockIdx.x * blockDim.x + threadIdx.x;
    int base = i * 4;
    if (base >= n_edges) return;
    if (base + 4 <= n_edges) {
        int4 s = *(const int4*)(src + base);
        int4 d = *(const int4*)(dst + base);
        int4 e = *(const int4*)(etype + base);
        int p;
        p = atomicAdd(cnt + s.x, 1); if (p < ELLW) ell[s.x * ELLW + p] = d.x | (e.x << 20);
        p = atomicAdd(cnt + s.y, 1); if (p < ELLW) ell[s.y * ELLW + p] = d.y | (e.y << 20);
        p = atomicAdd(cnt + s.z, 1); if (p < ELLW) ell[s.z * ELLW + p] = d.z | (e.z << 20);
        p = atomicAdd(cnt + s.w, 1); if (p < ELLW) ell[s.w * ELLW + p] = d.w | (e.w << 20);
    } else {
        for (int k = base; k < n_edges; ++k) {
            int p = atomicAdd(cnt + src[k], 1);
            if (p < ELLW) ell[src[k] * ELLW + p] = dst[k] | (etype[k] << 20);
        }
    }
}

// ---- aggregation: one wave per node; 4 subgroups x 16 lanes; 8 elems/lane;
//      software-pipelined: next-iter gathers issue into dead row regs, then
//      the long transcendental chain overlaps them ----
__global__ __launch_bounds__(256)
void node_agg_kernel(const float* __restrict__ slot,
                     const float* __restrict__ intm_virt,  // intm - n_slot*D
                     const float* __restrict__ rel,
                     const int* __restrict__ ell,
                     const int* __restrict__ cnt,
                     float* __restrict__ out,
                     int n_slot, int n_nodes) {
    int wid  = (blockIdx.x * blockDim.x + threadIdx.x) >> 6;
    int lane = threadIdx.x & 63;
    if (wid >= n_nodes) return;
    int sl = lane & 15;
    int g  = lane >> 4;

    // ---- per-node invariants: x = expmap0(embed[node]) ----
    const float* xrow = ((wid < n_slot) ? slot : intm_virt) + (size_t)wid * D + sl * 8;
    v2x2 ea = ld8(xrow);
    v2x2 eb = ld8(xrow + 4);
    v2f ssv = ea.lo * ea.lo;
    ssv = vfma2(ea.hi, ea.hi, ssv);
    ssv = vfma2(eb.lo, eb.lo, ssv);
    ssv = vfma2(eb.hi, eb.hi, ssv);
    float ss = red16(ssv.x + ssv.y);

    float irn = rsqf(fmaxf(ss, EPSF));
    float thn = tanh_exp2(LOG2E2 * ss * irn);   // tanh(||embed||)
    float tf  = thn * irn;                       // tanh(n)/n
    float x2  = thn * thn;                       // ||x||^2
    v2f tfv = (v2f){tf, tf};
    v2f x0 = ea.lo * tfv, x1 = ea.hi * tfv;
    v2f x2v_ = eb.lo * tfv, x3 = eb.hi * tfv;

    float fac  = 1.0f - x2;
    float fac2 = fac * fac;

    int cn = cnt[wid];
    int m  = (cn < ELLW) ? cn : ELLW;
    const int* erow = ell + (size_t)wid * ELLW;

    // whole ELL row into registers (one coalesced load per wave)
    int pk_all = (lane < m) ? erow[lane] : 0;

    float accx = 0.0f;
    v2f ac0 = (v2f){0.f, 0.f}, ac1 = ac0, ac2 = ac0, ac3 = ac0;

    if (m > 0) {
        // prologue: gather rows for iteration 0
        int pk = __shfl(pk_all, g, 64);
        unsigned di = (unsigned)pk & 0xFFFFF;
        unsigned ri = ((unsigned)pk) >> 20;
        const float* drow = (((int)di < n_slot) ? slot : intm_virt)
                            + (size_t)di * D + sl * 8;
        const float* rrow = rel + (size_t)ri * D + sl * 8;
        v2x2 dA = ld8(drow), dB = ld8(drow + 4);
        v2x2 rA = ld8(rrow), rB = ld8(rrow + 4);

        for (int p = 0; p < m; p += 4) {
            bool ok = (p + g) < m;

            // ---- phase 1: consume row regs -> tangent + reductions ----
            v2f t0 = dA.lo + rA.lo;
            v2f t1 = dA.hi + rA.hi;
            v2f t2 = dB.lo + rB.lo;
            v2f t3 = dB.hi + rB.hi;

            v2f ttv = t0 * t0;
            ttv = vfma2(t1, t1, ttv);
            ttv = vfma2(t2, t2, ttv);
            ttv = vfma2(t3, t3, ttv);
            v2f xtv = x0 * t0;
            xtv = vfma2(x1, t1, xtv);
            xtv = vfma2(x2v_, t2, xtv);
            xtv = vfma2(x3, t3, xtv);

            float tt = red16(ttv.x + ttv.y);
            float xt = red16(xtv.x + xtv.y);

            // ---- phase 2: row regs dead -> issue NEXT iteration's gathers ----
            if (p + 4 < m) {
                int pk2 = __shfl(pk_all, (p + 4 + g) & 63, 64);
                unsigned di2 = (unsigned)pk2 & 0xFFFFF;
                unsigned ri2 = ((unsigned)pk2) >> 20;
                const float* drow2 = (((int)di2 < n_slot) ? slot : intm_virt)
                                     + (size_t)di2 * D + sl * 8;
                const float* rrow2 = rel + (size_t)ri2 * D + sl * 8;
                dA = ld8(drow2); dB = ld8(drow2 + 4);
                rA = ld8(rrow2); rB = ld8(rrow2 + 4);
            }

            // ---- phase 3: long scalar chain (overlaps the gathers) ----
            float irt = rsqf(fmaxf(tt, EPSF));
            float th  = tanh_exp2(LOG2E2 * tt * irt);   // tanh(||t||)
            float w   = th * irt;                        // tanh(||t||)/||t||
            float y2  = th * th;                         // ||second||^2
            float xy  = w * xt;                          // x . second
            float two_xy = xy + xy;
            float opx = 1.0f + two_xy;
            float a   = opx + y2;
            float den = fmaf(x2, y2, opx);
            float invden = rcpf(fmaxf(den, EPSF));
            float poly = fmaf(a * a, x2, fmaf(a * fac, two_xy, fac2 * y2));
            float qq   = invden * invden * poly;         // ||q||^2
            float irq  = rsqf(fmaxf(qq, EPSF));
            float nq   = qq * irq;
            float cl   = fminf(nq, 1.0f - CLAMPF);
            float at   = HALF_LN2 * log2h((1.0f + cl) * rcpf(1.0f - cl)); // artanh
            float sc2  = at * irq;
            float k    = sc2 * invden;
            float cx   = k * a;
            float ct   = k * w * fac;
            if (!ok) { cx = 0.0f; ct = 0.0f; }

            accx += cx;
            v2f ctv = (v2f){ct, ct};
            ac0 = vfma2(ctv, t0, ac0);
            ac1 = vfma2(ctv, t1, ac1);
            ac2 = vfma2(ctv, t2, ac2);
            ac3 = vfma2(ctv, t3, ac3);
        }
    }

    // fold accx*x into accumulators (x identical across subgroups)
    v2f axv = (v2f){accx, accx};
    ac0 = vfma2(axv, x0, ac0);
    ac1 = vfma2(axv, x1, ac1);
    ac2 = vfma2(axv, x2v_, ac2);
    ac3 = vfma2(axv, x3, ac3);

    // cross-subgroup reduction (xor 16, 32)
    float v0 = ac0.x, v1 = ac0.y, v2 = ac1.x, v3 = ac1.y;
    float v4 = ac2.x, v5 = ac2.y, v6 = ac3.x, v7 = ac3.y;
    #pragma unroll
    for (int d = 16; d < 64; d <<= 1) {
        v0 += __shfl_xor(v0, d, 64);
        v1 += __shfl_xor(v1, d, 64);
        v2 += __shfl_xor(v2, d, 64);
        v3 += __shfl_xor(v3, d, 64);
        v4 += __shfl_xor(v4, d, 64);
        v5 += __shfl_xor(v5, d, 64);
        v6 += __shfl_xor(v6, d, 64);
        v7 += __shfl_xor(v7, d, 64);
    }

    if (lane < 16) {
        float invcnt = rcpf(fmaxf((float)cn, 1.0f));
        float4 w0 = make_float4(v0 * invcnt, v1 * invcnt, v2 * invcnt, v3 * invcnt);
        float4 w1 = make_float4(v4 * invcnt, v5 * invcnt, v6 * invcnt, v7 * invcnt);
        float* orow = out + (size_t)wid * D + sl * 8;
        *(float4*)(orow)     = w0;
        *(float4*)(orow + 4) = w1;
    }
}

extern "C" void kernel_launch(void* const* d_in, const int* in_sizes, int n_in,
                              void* d_out, int out_size, void* d_ws, size_t ws_size,
                              hipStream_t stream) {
    const float* slot = (const float*)d_in[0];
    const float* intm = (const float*)d_in[1];
    const float* rel  = (const float*)d_in[2];
    const int*   src  = (const int*)d_in[3];
    const int*   dst  = (const int*)d_in[4];
    const int*   etyp = (const int*)d_in[5];

    int n_slot  = in_sizes[0] / D;
    int n_int   = in_sizes[1] / D;
    int n_nodes = n_slot + n_int;
    int n_edges = in_sizes[3];

    float* out = (float*)d_out;
    const float* intm_virt = intm - (size_t)n_slot * D;

    int* cnt = (int*)d_ws;
    int* ell = cnt + n_nodes;

    (void)hipMemsetAsync(cnt, 0, (size_t)n_nodes * sizeof(int), stream);

    {   // one-pass ELL build (4 edges/thread)
        int threads = 256;
        int nthreads = (n_edges + 3) / 4;
        int blocks = (nthreads + threads - 1) / threads;
        build_ell_kernel<<<blocks, threads, 0, stream>>>(src, dst, etyp, cnt, ell,
                                                         n_edges);
    }
    {   // per-node aggregation
        int threads = 256;
        int blocks = (n_nodes * 64 + threads - 1) / threads;
        node_agg_kernel<<<blocks, threads, 0, stream>>>(slot, intm_virt, rel, ell,
                                                        cnt, out, n_slot, n_nodes);
    }
}